// Round 2
// baseline (662.259 us; speedup 1.0000x reference)
//
#include <hip/hip_runtime.h>
#include <math.h>

#define DIM   1024
#define HALF  512
#define NROWS 65536
#define NSLOTS 32

// ---- workspace layout (float offsets) ----
// zeroed region: [scal 8][qacc 512][wslots 32*1024][ovacc 1024][outacc 1024]
#define OFF_SCAL   0                       // scal[0]=sum(s) scal[1]=sum(s^2) scal[2]=sum(exp)
#define OFF_QACC   8
#define OFF_WSLOT  (OFF_QACC + HALF)
#define OFF_OVACC  (OFF_WSLOT + NSLOTS * DIM)
#define OFF_OUTACC (OFF_OVACC + DIM)
#define OFF_ZEND   (OFF_OUTACC + DIM)
// non-zeroed scratch
#define OFF_QN     OFF_ZEND
#define OFF_PVEC   (OFF_QN + DIM)
#define OFF_WACC   (OFF_PVEC + DIM)
#define OFF_S      (OFF_WACC + DIM)
#define OFF_INVN   (OFF_S + NROWS)
#define OFF_COEFF  (OFF_INVN + NROWS)
#define OFF_END    (OFF_COEFF + NROWS)

// K1: qn = q_init / max(||q_init||, 1e-12)
__global__ void k_qnorm(const float* __restrict__ q_init, float* __restrict__ qn) {
    __shared__ float red[1024];
    int t = threadIdx.x;
    float v = q_init[t];
    red[t] = v * v;
    __syncthreads();
    for (int s = 512; s > 0; s >>= 1) {
        if (t < s) red[t] += red[t + s];
        __syncthreads();
    }
    float inv = 1.0f / fmaxf(sqrtf(red[0]), 1e-12f);
    qn[t] = v * inv;
}

// Generic weighted column-sum: out[c] += sum_r (coeff[r] (+cbias[r])) * M[r][c]
// blockDim.x == ncols4 threads, each owns one float4 column group.
__global__ void k_colsum(const float* __restrict__ M,
                         const float* __restrict__ coeff,
                         const float* __restrict__ cbias,
                         float* __restrict__ out,
                         int ncols4, int rowsPerBlock) {
    int t = threadIdx.x;
    int r0 = blockIdx.x * rowsPerBlock;
    const float4* M4 = (const float4*)M + (size_t)r0 * ncols4 + t;
    float4 acc = make_float4(0.f, 0.f, 0.f, 0.f);
    #pragma unroll 8
    for (int r = 0; r < rowsPerBlock; ++r) {
        float c = coeff[r0 + r];
        if (cbias) c += cbias[r0 + r];
        float4 m = M4[(size_t)r * ncols4];
        acc.x += c * m.x; acc.y += c * m.y; acc.z += c * m.z; acc.w += c * m.w;
    }
    atomicAdd(&out[t * 4 + 0], acc.x);
    atomicAdd(&out[t * 4 + 1], acc.y);
    atomicAdd(&out[t * 4 + 2], acc.z);
    atomicAdd(&out[t * 4 + 3], acc.w);
}

// pvec[d] = sum_j Wk[d][j] * (qacc[j] + bq[j]); one wave per row d.
__global__ void k_pvec(const float* __restrict__ Wk,
                       const float* __restrict__ qacc,
                       const float* __restrict__ bq,
                       float* __restrict__ pvec) {
    __shared__ float q[HALF];
    int t = threadIdx.x; // 256
    for (int j = t; j < HALF; j += 256) q[j] = qacc[j] + bq[j];
    __syncthreads();
    int wave = t >> 6, lane = t & 63;
    int d = blockIdx.x * 4 + wave;
    const float* row = Wk + (size_t)d * HALF;
    float acc = 0.f;
    #pragma unroll
    for (int j0 = 0; j0 < HALF; j0 += 64) acc += row[j0 + lane] * q[j0 + lane];
    #pragma unroll
    for (int o = 32; o > 0; o >>= 1) acc += __shfl_down(acc, o);
    if (lane == 0) pvec[d] = acc;
}

// Pass 1: per row i: s_i = dot(k_init[i], pvec)/max(||k_init[i]||,eps), invn_i.
// 2 rows per wave (8 independent float4 loads/lane). Block = 256 thr = 8 rows.
// Also block-reduces sum(s), sum(s^2) -> 2 atomicAdds into scal.
__global__ void k_scores(const float* __restrict__ K,
                         const float* __restrict__ pvec,
                         float* __restrict__ svals,
                         float* __restrict__ invn,
                         float* __restrict__ scal) {
    __shared__ float4 p4[256];
    __shared__ float bsum[4], bssq[4];
    int t = threadIdx.x;
    p4[t] = ((const float4*)pvec)[t];
    __syncthreads();
    int wave = t >> 6, lane = t & 63;
    int row0 = blockIdx.x * 8 + wave * 2;
    const float4* kA = (const float4*)K + (size_t)row0 * 256;
    const float4* kB = kA + 256;
    float dotA = 0.f, sqA = 0.f, dotB = 0.f, sqB = 0.f;
    #pragma unroll
    for (int i = 0; i < 4; ++i) {
        int idx = lane + i * 64;
        float4 a = kA[idx];
        float4 b = kB[idx];
        float4 p = p4[idx];
        dotA += a.x * p.x + a.y * p.y + a.z * p.z + a.w * p.w;
        sqA  += a.x * a.x + a.y * a.y + a.z * a.z + a.w * a.w;
        dotB += b.x * p.x + b.y * p.y + b.z * p.z + b.w * p.w;
        sqB  += b.x * b.x + b.y * b.y + b.z * b.z + b.w * b.w;
    }
    #pragma unroll
    for (int o = 32; o > 0; o >>= 1) {
        dotA += __shfl_down(dotA, o);
        sqA  += __shfl_down(sqA, o);
        dotB += __shfl_down(dotB, o);
        sqB  += __shfl_down(sqB, o);
    }
    if (lane == 0) {
        float invA = 1.0f / fmaxf(sqrtf(sqA), 1e-12f);
        float invB = 1.0f / fmaxf(sqrtf(sqB), 1e-12f);
        float sA = dotA * invA, sB = dotB * invB;
        svals[row0]     = sA;  invn[row0]     = invA;
        svals[row0 + 1] = sB;  invn[row0 + 1] = invB;
        bsum[wave] = sA + sB;
        bssq[wave] = sA * sA + sB * sB;
    }
    __syncthreads();
    if (t == 0) {
        float s = bsum[0] + bsum[1] + bsum[2] + bsum[3];
        float q = bssq[0] + bssq[1] + bssq[2] + bssq[3];
        atomicAdd(&scal[0], s);
        atomicAdd(&scal[1], q);
    }
}

// coeff[i] = exp(clip((s_i-mean)/(std+1e-8), -10, 10)) * invn_i;
// block-reduced sum(exp) -> atomicAdd scal[2]. Grid 256 x 256 (1 elem/thread).
__global__ void k_coeff(const float* __restrict__ svals,
                        const float* __restrict__ invn,
                        float* __restrict__ coeff,
                        float* __restrict__ scal) {
    __shared__ float red[256];
    int t = threadIdx.x;
    int i = blockIdx.x * 256 + t;
    float mean = scal[0] / (float)NROWS;
    float var  = (scal[1] - (float)NROWS * mean * mean) / (float)(NROWS - 1);
    float rstd = 1.0f / (sqrtf(fmaxf(var, 0.0f)) + 1e-8f);
    float z = (svals[i] - mean) * rstd;
    z = fminf(fmaxf(z, -10.0f), 10.0f);
    float e = expf(z);
    coeff[i] = e * invn[i];
    red[t] = e;
    __syncthreads();
    for (int s = 128; s > 0; s >>= 1) {
        if (t < s) red[t] += red[t + s];
        __syncthreads();
    }
    if (t == 0) atomicAdd(&scal[2], red[0]);
}

// Pass 2: wslot[blockIdx&31][c] += sum_{r in block} coeff[r] * K[r][c]
// 4096 blocks x 256 thr, 16 fully-unrolled rows per block.
__global__ void k_wsum(const float* __restrict__ K,
                       const float* __restrict__ coeff,
                       float* __restrict__ wslots) {
    int t = threadIdx.x;
    int r0 = blockIdx.x * 16;
    const float4* M4 = (const float4*)K + (size_t)r0 * 256 + t;
    const float* cf = coeff + r0;
    float4 acc = make_float4(0.f, 0.f, 0.f, 0.f);
    #pragma unroll
    for (int r = 0; r < 16; ++r) {
        float c = cf[r];
        float4 m = M4[(size_t)r * 256];
        acc.x += c * m.x; acc.y += c * m.y; acc.z += c * m.z; acc.w += c * m.w;
    }
    float* slot = wslots + (size_t)(blockIdx.x & (NSLOTS - 1)) * DIM;
    atomicAdd(&slot[t * 4 + 0], acc.x);
    atomicAdd(&slot[t * 4 + 1], acc.y);
    atomicAdd(&slot[t * 4 + 2], acc.z);
    atomicAdd(&slot[t * 4 + 3], acc.w);
}

// wacc[c] = (sum_slots wslots[s][c]) / sum(exp). 1 block x 1024 threads.
__global__ void k_wreduce(const float* __restrict__ wslots,
                          const float* __restrict__ scal,
                          float* __restrict__ wacc) {
    int t = threadIdx.x;
    float acc = 0.f;
    #pragma unroll
    for (int s = 0; s < NSLOTS; ++s) acc += wslots[(size_t)s * DIM + t];
    wacc[t] = acc / scal[2];
}

// out = g*q_init + (1-g)*(outacc + bm), g = sigmoid(gamma)
__global__ void k_final(const float* __restrict__ q_init,
                        const float* __restrict__ outacc,
                        const float* __restrict__ bm,
                        const float* __restrict__ gamma,
                        float* __restrict__ out) {
    int t = threadIdx.x;
    float g = 1.0f / (1.0f + expf(-gamma[0]));
    out[t] = g * q_init[t] + (1.0f - g) * (outacc[t] + bm[t]);
}

extern "C" void kernel_launch(void* const* d_in, const int* in_sizes, int n_in,
                              void* d_out, int out_size, void* d_ws, size_t ws_size,
                              hipStream_t stream) {
    const float* q_init = (const float*)d_in[0];
    const float* k_init = (const float*)d_in[1];
    const float* Wq     = (const float*)d_in[2];
    const float* bq     = (const float*)d_in[3];
    const float* Wk     = (const float*)d_in[4];
    // d_in[5] = bk: constant shift of all scores -> cancels in standardization
    const float* Wv     = (const float*)d_in[6];
    const float* bv     = (const float*)d_in[7];
    const float* Wm     = (const float*)d_in[8];
    const float* bm     = (const float*)d_in[9];
    const float* gamma  = (const float*)d_in[10];
    float* out = (float*)d_out;
    float* ws  = (float*)d_ws;

    float* scal   = ws + OFF_SCAL;
    float* qacc   = ws + OFF_QACC;
    float* wslots = ws + OFF_WSLOT;
    float* ovacc  = ws + OFF_OVACC;
    float* outacc = ws + OFF_OUTACC;
    float* qn     = ws + OFF_QN;
    float* pvec   = ws + OFF_PVEC;
    float* wacc   = ws + OFF_WACC;
    float* svals  = ws + OFF_S;
    float* invn   = ws + OFF_INVN;
    float* coeff  = ws + OFF_COEFF;

    // zero all atomic accumulators in one memset
    hipMemsetAsync(ws, 0, (size_t)OFF_ZEND * sizeof(float), stream);

    k_qnorm<<<1, 1024, 0, stream>>>(q_init, qn);
    // q = qn @ Wq (column sum of Wq weighted by qn); bq folded in at k_pvec
    k_colsum<<<128, 128, 0, stream>>>(Wq, qn, nullptr, qacc, HALF / 4, DIM / 128);
    // pvec = Wk @ (q + bq)
    k_pvec<<<DIM / 4, 256, 0, stream>>>(Wk, qacc, bq, pvec);
    // pass 1 over k_init: scores + inv norms + fused mean/ssq stats
    k_scores<<<NROWS / 8, 256, 0, stream>>>(k_init, pvec, svals, invn, scal);
    // per-row coefficients + sum(exp)
    k_coeff<<<NROWS / 256, 256, 0, stream>>>(svals, invn, coeff, scal);
    // pass 2 over k_init: slot-replicated weighted column sum
    k_wsum<<<NROWS / 16, 256, 0, stream>>>(k_init, coeff, wslots);
    // fold slots + normalize by sum(exp)
    k_wreduce<<<1, 1024, 0, stream>>>(wslots, scal, wacc);
    // ov = w @ Wv (bv folded into next stage)
    k_colsum<<<128, 256, 0, stream>>>(Wv, wacc, nullptr, ovacc, DIM / 4, DIM / 128);
    // outacc = (ov + bv) @ Wm
    k_colsum<<<128, 256, 0, stream>>>(Wm, ovacc, bv, outacc, DIM / 4, DIM / 128);
    // out = g*q_init + (1-g)*(outacc + bm)
    k_final<<<1, 1024, 0, stream>>>(q_init, outacc, bm, gamma, out);
}

// Round 3
// 462.047 us; speedup vs baseline: 1.4333x; 1.4333x over previous
//
#include <hip/hip_runtime.h>
#include <math.h>

#define DIM   1024
#define HALF  512
#define NROWS 65536
#define SBLK  4096   // k_scores blocks (16 rows each)
#define WBLK  1024   // k_wsum blocks (64 rows each)
#define WF1   32     // fold-1 slots

// ---- workspace layout (float offsets), all atomic-free, no memset needed ----
#define OFF_QN     0
#define OFF_QACC   (OFF_QN + DIM)
#define OFF_PVEC   (OFF_QACC + HALF)
#define OFF_SCAL   (OFF_PVEC + DIM)          // [0]=mean [1]=rstd
#define OFF_PSTAT  (OFF_SCAL + 8)            // float2[SBLK]
#define OFF_S      (OFF_PSTAT + 2*SBLK)
#define OFF_INVN   (OFF_S + NROWS)
#define OFF_COEFF  (OFF_INVN + NROWS)
#define OFF_ESUM   (OFF_COEFF + NROWS)       // [256]
#define OFF_PW     (OFF_ESUM + 256)          // [WBLK*DIM] = 4 MB
#define OFF_P2     (OFF_PW + WBLK*DIM)       // [WF1*DIM]
#define OFF_WACC   (OFF_P2 + WF1*DIM)
#define OFF_OVACC  (OFF_WACC + DIM)
#define OFF_OUTACC (OFF_OVACC + DIM)
#define OFF_END    (OFF_OUTACC + DIM)

// qn = q_init / max(||q_init||, 1e-12)
__global__ void k_qnorm(const float* __restrict__ q_init, float* __restrict__ qn) {
    __shared__ float red[1024];
    int t = threadIdx.x;
    float v = q_init[t];
    red[t] = v * v;
    __syncthreads();
    for (int s = 512; s > 0; s >>= 1) {
        if (t < s) red[t] += red[t + s];
        __syncthreads();
    }
    float inv = 1.0f / fmaxf(sqrtf(red[0]), 1e-12f);
    qn[t] = v * inv;
}

// out[c4] = sum_r (coeff[r] (+cbias[r])) * M[r][c4]; one block per float4-column.
// LDS tree reduce, direct store — no atomics. Grid = ncols4 blocks x 256 thr.
__global__ void k_matvec_col(const float* __restrict__ M,
                             const float* __restrict__ coeff,
                             const float* __restrict__ cbias,
                             float* __restrict__ out,
                             int nrows, int ncols4) {
    __shared__ float4 red[256];
    int t = threadIdx.x, c4 = blockIdx.x;
    const float4* M4 = (const float4*)M;
    float4 acc = make_float4(0.f, 0.f, 0.f, 0.f);
    for (int r = t; r < nrows; r += 256) {
        float c = coeff[r];
        if (cbias) c += cbias[r];
        float4 m = M4[(size_t)r * ncols4 + c4];
        acc.x += c * m.x; acc.y += c * m.y; acc.z += c * m.z; acc.w += c * m.w;
    }
    red[t] = acc;
    __syncthreads();
    for (int s = 128; s > 0; s >>= 1) {
        if (t < s) {
            red[t].x += red[t + s].x; red[t].y += red[t + s].y;
            red[t].z += red[t + s].z; red[t].w += red[t + s].w;
        }
        __syncthreads();
    }
    if (t == 0) ((float4*)out)[c4] = red[0];
}

// pvec[d] = sum_j Wk[d][j] * (qacc[j] + bq[j]); one wave per row d.
__global__ void k_pvec(const float* __restrict__ Wk,
                       const float* __restrict__ qacc,
                       const float* __restrict__ bq,
                       float* __restrict__ pvec) {
    __shared__ float q[HALF];
    int t = threadIdx.x; // 256
    for (int j = t; j < HALF; j += 256) q[j] = qacc[j] + bq[j];
    __syncthreads();
    int wave = t >> 6, lane = t & 63;
    int d = blockIdx.x * 4 + wave;
    const float* row = Wk + (size_t)d * HALF;
    float acc = 0.f;
    #pragma unroll
    for (int j0 = 0; j0 < HALF; j0 += 64) acc += row[j0 + lane] * q[j0 + lane];
    #pragma unroll
    for (int o = 32; o > 0; o >>= 1) acc += __shfl_down(acc, o);
    if (lane == 0) pvec[d] = acc;
}

// Pass 1: 4 rows per wave (16 float4 loads in flight / lane).
// Per-block (sum s, sum s^2) stored to pstat[blockIdx] — NO atomics.
__global__ void k_scores(const float* __restrict__ K,
                         const float* __restrict__ pvec,
                         float* __restrict__ svals,
                         float* __restrict__ invn,
                         float2* __restrict__ pstat) {
    __shared__ float4 p4s[256];
    __shared__ float wsum[4], wssq[4];
    int t = threadIdx.x;
    p4s[t] = ((const float4*)pvec)[t];
    __syncthreads();
    int wave = t >> 6, lane = t & 63;
    int row0 = blockIdx.x * 16 + wave * 4;
    const float4* k4 = (const float4*)K + (size_t)row0 * 256;
    float d0 = 0, d1 = 0, d2 = 0, d3 = 0;
    float q0 = 0, q1 = 0, q2 = 0, q3 = 0;
    #pragma unroll
    for (int i = 0; i < 4; ++i) {
        int idx = lane + i * 64;
        float4 p = p4s[idx];
        float4 a = k4[idx];
        float4 b = k4[256 + idx];
        float4 c = k4[512 + idx];
        float4 e = k4[768 + idx];
        d0 += a.x * p.x + a.y * p.y + a.z * p.z + a.w * p.w;
        q0 += a.x * a.x + a.y * a.y + a.z * a.z + a.w * a.w;
        d1 += b.x * p.x + b.y * p.y + b.z * p.z + b.w * p.w;
        q1 += b.x * b.x + b.y * b.y + b.z * b.z + b.w * b.w;
        d2 += c.x * p.x + c.y * p.y + c.z * p.z + c.w * p.w;
        q2 += c.x * c.x + c.y * c.y + c.z * c.z + c.w * c.w;
        d3 += e.x * p.x + e.y * p.y + e.z * p.z + e.w * p.w;
        q3 += e.x * e.x + e.y * e.y + e.z * e.z + e.w * e.w;
    }
    #pragma unroll
    for (int o = 32; o > 0; o >>= 1) {
        d0 += __shfl_down(d0, o); q0 += __shfl_down(q0, o);
        d1 += __shfl_down(d1, o); q1 += __shfl_down(q1, o);
        d2 += __shfl_down(d2, o); q2 += __shfl_down(q2, o);
        d3 += __shfl_down(d3, o); q3 += __shfl_down(q3, o);
    }
    if (lane == 0) {
        float i0 = 1.0f / fmaxf(sqrtf(q0), 1e-12f);
        float i1 = 1.0f / fmaxf(sqrtf(q1), 1e-12f);
        float i2 = 1.0f / fmaxf(sqrtf(q2), 1e-12f);
        float i3 = 1.0f / fmaxf(sqrtf(q3), 1e-12f);
        float s0 = d0 * i0, s1 = d1 * i1, s2 = d2 * i2, s3 = d3 * i3;
        float4 sv = make_float4(s0, s1, s2, s3);
        float4 iv = make_float4(i0, i1, i2, i3);
        *(float4*)(svals + row0) = sv;
        *(float4*)(invn + row0) = iv;
        wsum[wave] = s0 + s1 + s2 + s3;
        wssq[wave] = s0 * s0 + s1 * s1 + s2 * s2 + s3 * s3;
    }
    __syncthreads();
    if (t == 0)
        pstat[blockIdx.x] = make_float2(wsum[0] + wsum[1] + wsum[2] + wsum[3],
                                        wssq[0] + wssq[1] + wssq[2] + wssq[3]);
}

// Reduce SBLK partial stats -> scal[0]=mean, scal[1]=rstd. 1 block x 1024.
__global__ void k_redstats(const float2* __restrict__ pstat, float* __restrict__ scal) {
    __shared__ float rs[1024], rq[1024];
    int t = threadIdx.x;
    float s = 0.f, q = 0.f;
    for (int i = t; i < SBLK; i += 1024) {
        float2 p = pstat[i];
        s += p.x; q += p.y;
    }
    rs[t] = s; rq[t] = q;
    __syncthreads();
    for (int k = 512; k > 0; k >>= 1) {
        if (t < k) { rs[t] += rs[t + k]; rq[t] += rq[t + k]; }
        __syncthreads();
    }
    if (t == 0) {
        float mean = rs[0] / (float)NROWS;
        float var  = (rq[0] - (float)NROWS * mean * mean) / (float)(NROWS - 1);
        scal[0] = mean;
        scal[1] = 1.0f / (sqrtf(fmaxf(var, 0.0f)) + 1e-8f);
    }
}

// coeff[i] = exp(clip((s-mean)*rstd,-10,10)) * invn[i]; per-block esum store.
__global__ void k_coeff(const float* __restrict__ svals,
                        const float* __restrict__ invn,
                        const float* __restrict__ scal,
                        float* __restrict__ coeff,
                        float* __restrict__ esum) {
    __shared__ float red[256];
    int t = threadIdx.x;
    int i = blockIdx.x * 256 + t;
    float mean = scal[0], rstd = scal[1];
    float z = (svals[i] - mean) * rstd;
    z = fminf(fmaxf(z, -10.0f), 10.0f);
    float e = expf(z);
    coeff[i] = e * invn[i];
    red[t] = e;
    __syncthreads();
    for (int s = 128; s > 0; s >>= 1) {
        if (t < s) red[t] += red[t + s];
        __syncthreads();
    }
    if (t == 0) esum[blockIdx.x] = red[0];
}

// Pass 2: per-block private partial column sums, stored (no atomics).
// WBLK blocks x 256 thr, 64 rows each, unroll 16.
__global__ void k_wsum(const float* __restrict__ K,
                       const float* __restrict__ coeff,
                       float* __restrict__ pw) {
    int t = threadIdx.x;
    int r0 = blockIdx.x * 64;
    const float4* M4 = (const float4*)K + (size_t)r0 * 256 + t;
    const float* cf = coeff + r0;
    float4 acc = make_float4(0.f, 0.f, 0.f, 0.f);
    #pragma unroll 16
    for (int r = 0; r < 64; ++r) {
        float c = cf[r];
        float4 m = M4[(size_t)r * 256];
        acc.x += c * m.x; acc.y += c * m.y; acc.z += c * m.z; acc.w += c * m.w;
    }
    ((float4*)pw)[(size_t)blockIdx.x * 256 + t] = acc;
}

// Fold WBLK partials -> WF1 partials. WF1 blocks x 256 thr.
__global__ void k_wfold(const float* __restrict__ pw, float* __restrict__ p2) {
    int t = threadIdx.x, b = blockIdx.x;
    const float4* pw4 = (const float4*)pw;
    float4 acc = make_float4(0.f, 0.f, 0.f, 0.f);
    #pragma unroll
    for (int p = 0; p < WBLK / WF1; ++p) {
        float4 m = pw4[(size_t)(b * (WBLK / WF1) + p) * 256 + t];
        acc.x += m.x; acc.y += m.y; acc.z += m.z; acc.w += m.w;
    }
    ((float4*)p2)[b * 256 + t] = acc;
}

// Fold WF1 partials + reduce esum[256] -> wacc = w / sum(exp). 1 block x 1024.
__global__ void k_wreduce(const float* __restrict__ p2,
                          const float* __restrict__ esum,
                          float* __restrict__ wacc) {
    __shared__ float red[256];
    int t = threadIdx.x;
    if (t < 256) red[t] = esum[t];
    __syncthreads();
    for (int s = 128; s > 0; s >>= 1) {
        if (t < s) red[t] += red[t + s];
        __syncthreads();
    }
    float inv = 1.0f / red[0];
    float acc = 0.f;
    #pragma unroll
    for (int b = 0; b < WF1; ++b) acc += p2[b * DIM + t];
    wacc[t] = acc * inv;
}

// out = g*q_init + (1-g)*(outacc + bm), g = sigmoid(gamma)
__global__ void k_final(const float* __restrict__ q_init,
                        const float* __restrict__ outacc,
                        const float* __restrict__ bm,
                        const float* __restrict__ gamma,
                        float* __restrict__ out) {
    int t = threadIdx.x;
    float g = 1.0f / (1.0f + expf(-gamma[0]));
    out[t] = g * q_init[t] + (1.0f - g) * (outacc[t] + bm[t]);
}

extern "C" void kernel_launch(void* const* d_in, const int* in_sizes, int n_in,
                              void* d_out, int out_size, void* d_ws, size_t ws_size,
                              hipStream_t stream) {
    const float* q_init = (const float*)d_in[0];
    const float* k_init = (const float*)d_in[1];
    const float* Wq     = (const float*)d_in[2];
    const float* bq     = (const float*)d_in[3];
    const float* Wk     = (const float*)d_in[4];
    // d_in[5] = bk: constant shift of all scores -> cancels in standardization
    const float* Wv     = (const float*)d_in[6];
    const float* bv     = (const float*)d_in[7];
    const float* Wm     = (const float*)d_in[8];
    const float* bm     = (const float*)d_in[9];
    const float* gamma  = (const float*)d_in[10];
    float* out = (float*)d_out;
    float* ws  = (float*)d_ws;

    float*  qn     = ws + OFF_QN;
    float*  qacc   = ws + OFF_QACC;
    float*  pvec   = ws + OFF_PVEC;
    float*  scal   = ws + OFF_SCAL;
    float2* pstat  = (float2*)(ws + OFF_PSTAT);
    float*  svals  = ws + OFF_S;
    float*  invn   = ws + OFF_INVN;
    float*  coeff  = ws + OFF_COEFF;
    float*  esum   = ws + OFF_ESUM;
    float*  pw     = ws + OFF_PW;
    float*  p2     = ws + OFF_P2;
    float*  wacc   = ws + OFF_WACC;
    float*  ovacc  = ws + OFF_OVACC;
    float*  outacc = ws + OFF_OUTACC;

    k_qnorm<<<1, 1024, 0, stream>>>(q_init, qn);
    // q = qn @ Wq (bq folded in at k_pvec)
    k_matvec_col<<<HALF / 4, 256, 0, stream>>>(Wq, qn, nullptr, qacc, DIM, HALF / 4);
    // pvec = Wk @ (q + bq)
    k_pvec<<<DIM / 4, 256, 0, stream>>>(Wk, qacc, bq, pvec);
    // pass 1: scores + inv norms + per-block stats partials
    k_scores<<<SBLK, 256, 0, stream>>>(k_init, pvec, svals, invn, pstat);
    k_redstats<<<1, 1024, 0, stream>>>(pstat, scal);
    k_coeff<<<NROWS / 256, 256, 0, stream>>>(svals, invn, scal, coeff, esum);
    // pass 2: private partials -> two-level fold
    k_wsum<<<WBLK, 256, 0, stream>>>(k_init, coeff, pw);
    k_wfold<<<WF1, 256, 0, stream>>>(pw, p2);
    k_wreduce<<<1, 1024, 0, stream>>>(p2, esum, wacc);
    // ov = w @ Wv ; outacc = (ov + bv) @ Wm
    k_matvec_col<<<DIM / 4, 256, 0, stream>>>(Wv, wacc, nullptr, ovacc, DIM, DIM / 4);
    k_matvec_col<<<DIM / 4, 256, 0, stream>>>(Wm, ovacc, bv, outacc, DIM, DIM / 4);
    k_final<<<1, 1024, 0, stream>>>(q_init, outacc, bm, gamma, out);
}